// Round 6
// baseline (4258.518 us; speedup 1.0000x reference)
//
#include <hip/hip_runtime.h>
#include <math.h>

#define BB 8
#define TT 12
#define NN 716
#define EE 10
#define HH 64
#define DIN 65
#define OG 128
#define OU 64
#define XSP 68     // padded xs / parts row stride
#define JS 12      // j-split for xg2 gemm
#define JRX 60     // j per split (12*60=720 >= 716)
#define NTN 128    // n-tile in xg2
#define NP 768     // padded n for parts
#define NI4 17     // ceil(DIN/4) i4 slots in w4 layout

__device__ __forceinline__ float sigmf(float x){ return 1.0f/(1.0f+__expf(-x)); }

// ---------------- emb precompute + cur0 ----------------
__global__ void k_emb(const float* __restrict__ src, const float* __restrict__ ne,
                      const float* __restrict__ te, const float* __restrict__ de,
                      float* __restrict__ emb, float* __restrict__ cur){
  int idx = blockIdx.x*256 + threadIdx.x;
  if (idx >= BB*TT*NN) return;
  int n = idx % NN; int t = (idx/NN) % TT; int b = idx/(NN*TT);
  const float* s = src + (size_t)idx*3;
  float x = s[0];
  int ti = (int)(s[1]*288.0f);
  int di = (int)(s[2]);
  size_t eo = ((size_t)b*TT + t)*NN*EE + (size_t)n*EE;
  #pragma unroll
  for (int e=0;e<EE;e++)
    emb[eo+e] = ne[n*EE+e]*te[ti*EE+e]*de[di*EE+e];
  cur[((size_t)t*BB + b)*NN + n] = x;   // cur[0][t][b][n]
}

// ---------------- per-layer w4[n][k][i4][O][4] = static@wp ----------------
template<int O>
__global__ __launch_bounds__(256) void k_prep_w4(
    const float* __restrict__ ne, const float* __restrict__ wp,
    float* __restrict__ w4)
{
  __shared__ float wps[EE*4*O];
  int ki4 = blockIdx.x;          // 0..33 : k*17+i4
  int nq  = blockIdx.y;          // 0..3
  int k = ki4/NI4, i4 = ki4 - k*NI4;
  int tid = threadIdx.x;
  for (int idx=tid; idx<EE*4*O; idx+=256){
    int e = idx/(4*O); int rem = idx - e*4*O; int sub = rem/O; int o = rem - sub*O;
    int i = i4*4 + sub;
    wps[idx] = (i<DIN) ? wp[(((size_t)e*2+k)*DIN+i)*O + o] : 0.f;
  }
  __syncthreads();
  constexpr int NG = 256/O;
  int o = tid & (O-1), ng = tid / O;
  int n1 = nq*179, n2 = min(NN, n1+179);
  for (int n = n1+ng; n < n2; n += NG){
    float4 a = {0.f,0.f,0.f,0.f};
    #pragma unroll
    for (int e=0;e<EE;e++){
      float nef = ne[n*EE+e];
      a.x += nef*wps[e*4*O + 0*O + o];
      a.y += nef*wps[e*4*O + 1*O + o];
      a.z += nef*wps[e*4*O + 2*O + o];
      a.w += nef*wps[e*4*O + 3*O + o];
    }
    ((float4*)w4)[((size_t)(n*2+k)*NI4 + i4)*O + o] = a;
  }
}

// ---------------- per-layer misc: biases + h=0 + xs/nv init ----------------
__global__ void k_misc(const float* __restrict__ ne,
                       const float* __restrict__ bp_g, const float* __restrict__ bp_u,
                       float* __restrict__ bg, float* __restrict__ bu,
                       float* __restrict__ h, const float* __restrict__ cur_c,
                       const float* __restrict__ f1W, const float* __restrict__ f1b,
                       const float* __restrict__ f2W, const float* __restrict__ f2b,
                       const float* __restrict__ f3W, const float* __restrict__ f3b,
                       const float* __restrict__ emb,
                       float* __restrict__ xsg, float* __restrict__ nv){
  int mt = blockIdx.x*256 + threadIdx.x;
  int MT = gridDim.x*256;
  for (int i=mt; i<BB*NN*HH; i+=MT) h[i] = 0.f;
  for (int i=mt; i<NN*OG; i+=MT){
    int o=i&(OG-1), n=i>>7; float a=0.f;
    #pragma unroll
    for (int e=0;e<EE;e++) a += ne[n*EE+e]*bp_g[e*OG+o];
    bg[i]=a;
  }
  for (int i=mt; i<NN*OU; i+=MT){
    int o=i&(OU-1), n=i>>6; float a=0.f;
    #pragma unroll
    for (int e=0;e<EE;e++) a += ne[n*EE+e]*bp_u[e*OU+o];
    bu[i]=a;
  }
  for (int idx=mt; idx<BB*NN; idx+=MT){
    int b=idx/NN, n=idx-b*NN;
    float x = cur_c[(size_t)b*NN + n];   // t = 0
    float* xr = xsg + (size_t)idx*XSP;
    xr[0]=x;
    #pragma unroll
    for (int i2=1;i2<XSP;i2++) xr[i2]=0.f;
    float h1[16];
    #pragma unroll
    for (int k=0;k<16;k++) h1[k]=sigmf(f1b[k]+f1W[k*DIN]*x);
    float h2[2];
    #pragma unroll
    for (int k=0;k<2;k++){
      float s=f2b[k];
      #pragma unroll
      for (int q=0;q<16;q++) s+=f2W[k*16+q]*h1[q];
      h2[k]=sigmf(s);
    }
    #pragma unroll
    for (int e=0;e<EE;e++){
      float xe=f3b[e]+f3W[e*2]*h2[0]+f3W[e*2+1]*h2[1];
      nv[(size_t)idx*EE+e]=tanhf(emb[(((size_t)b*TT+0)*NN+n)*EE+e]*xe);
    }
  }
}

// ---------------- fused d + xg2 gemm (G on the fly), 128n x 64i tile ----------------
// grid (nc=6, js=12, b=8); parts[js][b][n][i<=64], d[b][j] (redundant-identical across nc)
__global__ __launch_bounds__(256) void k_xg2d(
    const float* __restrict__ nv, const float* __restrict__ xs,
    float* __restrict__ parts, float* __restrict__ dout)
{
  __shared__ float a_nv[NTN*11];                 // 5.6 KB
  __shared__ float b_nv[64*11];                  // 2.8 KB
  __shared__ float dls[64];
  __shared__ __align__(16) float big[12800];     // 51.2 KB: nvs(7160) then xss|gs
  float* nvs = big;                              // [716][10]
  float (*xss)[XSP] = (float(*)[XSP])big;        // [64][68] = 4352
  float (*gs)[NTN+4] = (float(*)[NTN+4])(big + 4352); // [64][132] = 8448

  int nc = blockIdx.x, js = blockIdx.y, b = blockIdx.z;
  int tid = threadIdx.x;
  int n0 = nc*NTN;
  int j0 = js*JRX;
  int jend = min(NN, j0+JRX);
  int cnt = jend - j0;                // 60 or 56
  // ---- P0: stage full nv[b] into nvs (coalesced float4)
  {
    const float4* src4 = (const float4*)(nv + (size_t)b*NN*EE);
    for (int i=tid; i<NN*EE/4; i+=256) ((float4*)nvs)[i] = src4[i];
  }
  __syncthreads();
  // ---- P1: copy a_nv/b_nv slices (LDS->LDS) + register-blocked d for this j-range
  for (int idx=tid; idx<NTN*EE; idx+=256){
    int r = idx/EE, e = idx - r*EE;
    int n = n0 + r;
    a_nv[r*11+e] = (n<NN) ? nvs[n*EE+e] : 0.f;
  }
  for (int idx=tid; idx<64*EE; idx+=256){
    int r = idx/EE, e = idx - r*EE;
    b_nv[r*11+e] = (r<cnt) ? nvs[(j0+r)*EE+e] : 0.f;
  }
  {
    int jg = tid>>4, ns = tid&15;
    float bv[4][EE];
    #pragma unroll
    for (int r=0;r<4;r++){
      int jr = jg*4+r;
      bool ok = (jr < cnt);
      #pragma unroll
      for (int e=0;e<EE;e++) bv[r][e] = ok ? nvs[(j0+jr)*EE+e] : 0.f;
    }
    float sums[4]={0.f,0.f,0.f,0.f};
    for (int n=ns; n<NN; n+=16){
      float av[EE];
      #pragma unroll
      for (int e=0;e<EE;e++) av[e] = nvs[n*EE+e];
      #pragma unroll
      for (int r=0;r<4;r++){
        float s=0.f;
        #pragma unroll
        for (int e=0;e<EE;e++) s += bv[r][e]*av[e];
        sums[r] += fmaxf(s,0.f);
      }
    }
    #pragma unroll
    for (int r=0;r<4;r++){
      float s = sums[r];
      s += __shfl_xor(s,1,64); s += __shfl_xor(s,2,64);
      s += __shfl_xor(s,4,64); s += __shfl_xor(s,8,64);
      sums[r] = s;
    }
    if (ns==0){
      #pragma unroll
      for (int r=0;r<4;r++){
        int jr = jg*4+r;
        if (jr < cnt){
          float dv = rsqrtf(sums[r]);
          dls[jr] = dv;
          dout[b*NN + j0 + jr] = dv;
        }
      }
    }
  }
  __syncthreads();
  // ---- P2: xss staging (d_j-scaled) + G tile compute (overwrites nvs region)
  for (int idx=tid; idx<64*64; idx+=256){
    int r = idx>>6, ii = idx&63;
    xss[r][ii] = (r<cnt) ? dls[r]*xs[((size_t)b*NN+j0+r)*XSP+ii] : 0.f;
  }
  if (tid < 64)
    xss[tid][64] = (tid<cnt) ? dls[tid]*xs[((size_t)b*NN+j0+tid)*XSP+64] : 0.f;
  {
    int jg = tid>>4, ng3 = tid&15;
    float g[4][8];
    #pragma unroll
    for (int r=0;r<4;r++)
      #pragma unroll
      for (int s2=0;s2<8;s2++) g[r][s2]=0.f;
    #pragma unroll
    for (int e=0;e<EE;e++){
      float bv[4], av[8];
      #pragma unroll
      for (int r=0;r<4;r++) bv[r] = b_nv[(jg*4+r)*11+e];
      #pragma unroll
      for (int s2=0;s2<8;s2++) av[s2] = a_nv[(ng3*8+s2)*11+e];
      #pragma unroll
      for (int r=0;r<4;r++)
        #pragma unroll
        for (int s2=0;s2<8;s2++) g[r][s2] += bv[r]*av[s2];
    }
    #pragma unroll
    for (int r=0;r<4;r++){
      float4 v0 = { fmaxf(g[r][0],0.f), fmaxf(g[r][1],0.f),
                    fmaxf(g[r][2],0.f), fmaxf(g[r][3],0.f) };
      float4 v1 = { fmaxf(g[r][4],0.f), fmaxf(g[r][5],0.f),
                    fmaxf(g[r][6],0.f), fmaxf(g[r][7],0.f) };
      *(float4*)&gs[jg*4+r][ng3*8]   = v0;
      *(float4*)&gs[jg*4+r][ng3*8+4] = v1;
    }
  }
  __syncthreads();
  // ---- P3: main accumulation (ng: 4 n's, ig: 8 i's)
  int ng = tid >> 3, ig = tid & 7;
  float acc[4][8];
  #pragma unroll
  for (int r=0;r<4;r++)
    #pragma unroll
    for (int s2=0;s2<8;s2++) acc[r][s2]=0.f;
  for (int jj=0; jj<cnt; ++jj){
    float4 g4  = *(const float4*)&gs[jj][ng*4];
    float4 x4a = *(const float4*)&xss[jj][ig*8];
    float4 x4b = *(const float4*)&xss[jj][ig*8+4];
    float gr[4] = {g4.x, g4.y, g4.z, g4.w};
    float xr[8] = {x4a.x,x4a.y,x4a.z,x4a.w, x4b.x,x4b.y,x4b.z,x4b.w};
    #pragma unroll
    for (int r=0;r<4;r++)
      #pragma unroll
      for (int s2=0;s2<8;s2++) acc[r][s2] += gr[r]*xr[s2];
  }
  #pragma unroll
  for (int r=0;r<4;r++){
    int n = n0 + ng*4 + r;    // < NP always
    float4 v0 = { acc[r][0], acc[r][1], acc[r][2], acc[r][3] };
    float4 v1 = { acc[r][4], acc[r][5], acc[r][6], acc[r][7] };
    size_t base = (((size_t)js*BB+b)*NP+n)*XSP;
    *(float4*)&parts[base + ig*8]     = v0;
    *(float4*)&parts[base + ig*8 + 4] = v1;
  }
  if (tid < NTN){
    float s = 0.f;
    for (int jj=0; jj<cnt; ++jj) s += gs[jj][tid]*xss[jj][64];
    parts[(((size_t)js*BB+b)*NP + n0+tid)*XSP + 64] = s;
  }
}

// ---------------- gate transform (w4 float4 layout) ----------------
__global__ __launch_bounds__(256) void k_tr_gate(
    const float* __restrict__ wg, const float* __restrict__ bg,
    const float* __restrict__ parts, const float* __restrict__ d,
    const float* __restrict__ xsg,
    const float* __restrict__ cur_ct, const float* __restrict__ h,
    const float* __restrict__ emb, int t,
    const float* __restrict__ f1W, const float* __restrict__ f1b,
    const float* __restrict__ f2W, const float* __restrict__ f2b,
    const float* __restrict__ f3W, const float* __restrict__ f3b,
    float* __restrict__ rbuf, float* __restrict__ xsu, float* __restrict__ nv)
{
  __shared__ float xg2s[BB][XSP];
  __shared__ float xss[BB][XSP];
  __shared__ float cs[BB][DIN];
  __shared__ float h1s[BB][16];
  __shared__ float h2s[BB][2];
  int n = blockIdx.x;
  int tid = threadIdx.x;
  float dn = d[0*NN+n]; // per-b below
  (void)dn;
  for (int idx=tid; idx<BB*XSP; idx+=256){
    int b = idx/XSP, i = idx - b*XSP;
    float s = 0.f;
    if (i < 65){
      #pragma unroll
      for (int js2=0; js2<JS; js2++)
        s += parts[(((size_t)js2*BB+b)*NP+n)*XSP + i];
      s *= d[b*NN+n];
    }
    xg2s[b][i] = s;
  }
  for (int idx=tid; idx<BB*XSP; idx+=256){
    int b = idx/XSP, i = idx - b*XSP;
    xss[b][i] = (i<65) ? xsg[((size_t)b*NN+n)*XSP + i] : 0.f;
  }
  __syncthreads();
  {
    int o = tid & 127, half = tid >> 7;
    const float4* w0p = (const float4*)wg + ((size_t)n*2+0)*NI4*OG + o;
    const float4* w1p = w0p + (size_t)NI4*OG;
    float bgv = bg[n*OG+o];
    float acc[4]; acc[0]=bgv; acc[1]=bgv; acc[2]=bgv; acc[3]=bgv;
    #pragma unroll
    for (int i4=0;i4<NI4;i4++){
      float4 w0 = w0p[(size_t)i4*OG];
      float4 w1 = w1p[(size_t)i4*OG];
      int i = i4*4;
      #pragma unroll
      for (int bb=0;bb<4;bb++){
        int b = 2*bb+half;
        acc[bb] += xss[b][i]*w0.x + xss[b][i+1]*w0.y
                 + xss[b][i+2]*w0.z + xss[b][i+3]*w0.w
                 + xg2s[b][i]*w1.x + xg2s[b][i+1]*w1.y
                 + xg2s[b][i+2]*w1.z + xg2s[b][i+3]*w1.w;
      }
    }
    #pragma unroll
    for (int bb=0;bb<4;bb++){
      int b = 2*bb+half;
      float v = sigmf(acc[bb]);
      if (o < 64){
        float cv = v * h[((size_t)b*NN+n)*HH + o];
        xsu[((size_t)b*NN+n)*XSP + 1 + o] = cv;
        cs[b][1+o] = cv;
      } else {
        rbuf[((size_t)b*NN+n)*HH + (o-64)] = v;
      }
    }
    if (o == 64){
      #pragma unroll
      for (int bb=0;bb<4;bb++){
        int b = 2*bb+half;
        float x = cur_ct[(size_t)b*NN+n];
        cs[b][0] = x;
        xsu[((size_t)b*NN+n)*XSP] = x;
      }
    }
  }
  __syncthreads();
  if (tid < BB*16){
    int b=tid>>4, k=tid&15;
    const float* wr = f1W + k*DIN;
    float s = f1b[k];
    #pragma unroll
    for (int i=0;i<DIN;i++) s += cs[b][i]*wr[i];
    h1s[b][k] = sigmf(s);
  }
  __syncthreads();
  if (tid < BB*2){
    int b=tid>>1, k=tid&1;
    float s = f2b[k];
    #pragma unroll
    for (int q2=0;q2<16;q2++) s += h1s[b][q2]*f2W[k*16+q2];
    h2s[b][k] = sigmf(s);
  }
  __syncthreads();
  if (tid < BB*EE){
    int b=tid/EE, e=tid-b*EE;
    float xe = f3b[e] + f3W[e*2]*h2s[b][0] + f3W[e*2+1]*h2s[b][1];
    nv[((size_t)b*NN+n)*EE+e] = tanhf(emb[(((size_t)b*TT+t)*NN+n)*EE+e]*xe);
  }
}

// ---------------- update transform (w4 float4 layout) ----------------
__global__ __launch_bounds__(256) void k_tr_upd(
    const float* __restrict__ wu, const float* __restrict__ bu,
    const float* __restrict__ parts, const float* __restrict__ d,
    const float* __restrict__ xsu,
    const float* __restrict__ rbuf, float* __restrict__ h,
    float* __restrict__ cur, int c, int t,
    const float* __restrict__ emb,
    const float* __restrict__ f1W, const float* __restrict__ f1b,
    const float* __restrict__ f2W, const float* __restrict__ f2b,
    const float* __restrict__ f3W, const float* __restrict__ f3b,
    float* __restrict__ xsg, float* __restrict__ nv,
    const float* __restrict__ predW, const float* __restrict__ predB,
    const float* __restrict__ skipW, const float* __restrict__ skipB,
    float* __restrict__ out)
{
  __shared__ float xg2s[BB][XSP];
  __shared__ float xss[BB][XSP];
  __shared__ float hs[BB][HH];
  __shared__ float h1s[BB][16];
  __shared__ float h2s[BB][2];
  __shared__ float xns[BB];
  int n = blockIdx.x;
  int tid = threadIdx.x;
  for (int idx=tid; idx<BB*XSP; idx+=256){
    int b = idx/XSP, i = idx - b*XSP;
    float s = 0.f;
    if (i < 65){
      #pragma unroll
      for (int js2=0; js2<JS; js2++)
        s += parts[(((size_t)js2*BB+b)*NP+n)*XSP + i];
      s *= d[b*NN+n];
    }
    xg2s[b][i] = s;
  }
  for (int idx=tid; idx<BB*XSP; idx+=256){
    int b = idx/XSP, i = idx - b*XSP;
    xss[b][i] = (i<65) ? xsu[((size_t)b*NN+n)*XSP + i] : 0.f;
  }
  __syncthreads();
  {
    int o = tid & 63, grp = tid >> 6;
    const float4* w0p = (const float4*)wu + ((size_t)n*2+0)*NI4*OU + o;
    const float4* w1p = w0p + (size_t)NI4*OU;
    float acc[2];
    acc[0] = bu[n*OU+o]; acc[1] = acc[0];
    #pragma unroll
    for (int i4=0;i4<NI4;i4++){
      float4 w0 = w0p[(size_t)i4*OU];
      float4 w1 = w1p[(size_t)i4*OU];
      int i = i4*4;
      #pragma unroll
      for (int bb=0;bb<2;bb++){
        int b = grp + 4*bb;
        acc[bb] += xss[b][i]*w0.x + xss[b][i+1]*w0.y
                 + xss[b][i+2]*w0.z + xss[b][i+3]*w0.w
                 + xg2s[b][i]*w1.x + xg2s[b][i+1]*w1.y
                 + xg2s[b][i+2]*w1.z + xg2s[b][i+3]*w1.w;
      }
    }
    #pragma unroll
    for (int bb=0;bb<2;bb++){
      int b = grp + 4*bb;
      float hc = tanhf(acc[bb]);
      float r = rbuf[((size_t)b*NN+n)*HH+o];
      float hold = h[((size_t)b*NN+n)*HH+o];
      float hn = r*hold + (1.f-r)*hc;
      h[((size_t)b*NN+n)*HH+o] = hn;
      hs[b][o] = hn;
    }
  }
  __syncthreads();
  if (t < TT-1){
    if (tid < BB){
      float x = cur[(((size_t)c*TT + (t+1))*BB + tid)*NN + n];
      xns[tid] = x;
      xsg[((size_t)tid*NN+n)*XSP] = x;
    }
    for (int idx=tid; idx<BB*HH; idx+=256){
      int b = idx>>6, oo = idx&63;
      xsg[((size_t)b*NN+n)*XSP + 1 + oo] = hs[b][oo];
    }
    __syncthreads();
    if (tid < BB*16){
      int b=tid>>4, k=tid&15;
      const float* wr = f1W + k*DIN;
      float s = f1b[k] + wr[0]*xns[b];
      #pragma unroll
      for (int oo=0;oo<HH;oo++) s += hs[b][oo]*wr[1+oo];
      h1s[b][k] = sigmf(s);
    }
    __syncthreads();
    if (tid < BB*2){
      int b=tid>>1, k=tid&1;
      float s = f2b[k];
      #pragma unroll
      for (int q2=0;q2<16;q2++) s += h1s[b][q2]*f2W[k*16+q2];
      h2s[b][k] = sigmf(s);
    }
    __syncthreads();
    if (tid < BB*EE){
      int b=tid/EE, e=tid-b*EE;
      float xe = f3b[e] + f3W[e*2]*h2s[b][0] + f3W[e*2+1]*h2s[b][1];
      nv[((size_t)b*NN+n)*EE+e] =
        tanhf(emb[(((size_t)b*TT+(t+1))*NN+n)*EE+e]*xe);
    }
  } else {
    if (tid < BB*TT){
      int b = tid/TT, ot = tid - b*TT;
      const float* pw = predW + ((size_t)c*TT + ot)*HH;
      float pv = predB[c*TT+ot];
      #pragma unroll
      for (int q2=0;q2<HH;q2++) pv += hs[b][q2]*pw[q2];
      size_t oi = ((size_t)b*TT+ot)*NN + n;
      if (c == 0){
        out[oi] = pv;
        const float* sw = skipW + (size_t)ot*HH;
        float sk = skipB[ot];
        #pragma unroll
        for (int q2=0;q2<HH;q2++) sk += hs[b][q2]*sw[q2];
        cur[(((size_t)TT+ot)*BB + b)*NN + n] =
            cur[((size_t)ot*BB + b)*NN + n] - sk;
      } else {
        out[oi] += pv;
      }
    }
  }
}

extern "C" void kernel_launch(void* const* d_in, const int* in_sizes, int n_in,
                              void* d_out, int out_size, void* d_ws, size_t ws_size,
                              hipStream_t stream){
  const float* src  = (const float*)d_in[0];
  const float* ne   = (const float*)d_in[1];
  const float* te   = (const float*)d_in[2];
  const float* de   = (const float*)d_in[3];
  const float* wp_g = (const float*)d_in[4];
  const float* bp_g = (const float*)d_in[5];
  const float* f1W_g= (const float*)d_in[6];
  const float* f1b_g= (const float*)d_in[7];
  const float* f2W_g= (const float*)d_in[8];
  const float* f2b_g= (const float*)d_in[9];
  const float* f3W_g= (const float*)d_in[10];
  const float* f3b_g= (const float*)d_in[11];
  const float* wp_u = (const float*)d_in[12];
  const float* bp_u = (const float*)d_in[13];
  const float* f1W_u= (const float*)d_in[14];
  const float* f1b_u= (const float*)d_in[15];
  const float* f2W_u= (const float*)d_in[16];
  const float* f2b_u= (const float*)d_in[17];
  const float* f3W_u= (const float*)d_in[18];
  const float* f3b_u= (const float*)d_in[19];
  const float* predW= (const float*)d_in[20];
  const float* predB= (const float*)d_in[21];
  const float* skipW= (const float*)d_in[22];
  const float* skipB= (const float*)d_in[23];

  float* ws   = (float*)d_ws;
  float* emb  = ws;
  float* cur  = emb  + (size_t)BB*TT*NN*EE;
  float* wg   = cur  + (size_t)2*TT*BB*NN;
  float* bg   = wg   + (size_t)NN*2*NI4*OG*4;
  float* wu   = bg   + (size_t)NN*OG;
  float* bu   = wu   + (size_t)NN*2*NI4*OU*4;
  float* h    = bu   + (size_t)NN*OU;
  float* xsg  = h    + (size_t)BB*NN*HH;
  float* xsu  = xsg  + (size_t)BB*NN*XSP;
  float* nv   = xsu  + (size_t)BB*NN*XSP;
  float* dbuf = nv   + (size_t)BB*NN*EE;
  float* parts= dbuf + (size_t)BB*NN;
  float* rbuf = parts+ (size_t)JS*BB*NP*XSP;
  float* outp = (float*)d_out;

  k_emb<<<(BB*TT*NN+255)/256, 256, 0, stream>>>(src, ne, te, de, emb, cur);

  for (int c=0;c<2;c++){
    k_prep_w4<OG><<<dim3(2*NI4,4),256,0,stream>>>(ne, wp_g + (size_t)c*EE*2*DIN*OG, wg);
    k_prep_w4<OU><<<dim3(2*NI4,4),256,0,stream>>>(ne, wp_u + (size_t)c*EE*2*DIN*OU, wu);
    k_misc<<<1024,256,0,stream>>>(ne, bp_g + (size_t)c*EE*OG, bp_u + (size_t)c*EE*OU,
        bg, bu, h, cur + (size_t)c*TT*BB*NN,
        f1W_g + c*16*DIN, f1b_g + c*16, f2W_g + c*32, f2b_g + c*2,
        f3W_g + c*EE*2, f3b_g + c*EE, emb, xsg, nv);
    for (int t=0;t<TT;t++){
      k_xg2d<<<dim3(6,JS,BB),256,0,stream>>>(nv, xsg, parts, dbuf);
      k_tr_gate<<<NN,256,0,stream>>>(wg, bg, parts, dbuf, xsg,
          cur + ((size_t)c*TT+t)*BB*NN, h, emb, t,
          f1W_u + c*16*DIN, f1b_u + c*16, f2W_u + c*32, f2b_u + c*2,
          f3W_u + c*EE*2, f3b_u + c*EE, rbuf, xsu, nv);
      k_xg2d<<<dim3(6,JS,BB),256,0,stream>>>(nv, xsu, parts, dbuf);
      k_tr_upd<<<NN,256,0,stream>>>(wu, bu, parts, dbuf, xsu, rbuf, h,
          cur, c, t, emb,
          f1W_g + c*16*DIN, f1b_g + c*16, f2W_g + c*32, f2b_g + c*2,
          f3W_g + c*EE*2, f3b_g + c*EE,
          xsg, nv, predW, predB, skipW, skipB, outp);
    }
  }
}

// Round 7
// 3217.152 us; speedup vs baseline: 1.3237x; 1.3237x over previous
//
#include <hip/hip_runtime.h>
#include <math.h>

#define BB 8
#define TT 12
#define NN 716
#define EE 10
#define HH 64
#define DIN 65
#define OG 128
#define OU 64
#define XSP 68     // padded xs / parts row stride
#define JS 12      // j-split for xg2 gemm
#define JRX 60     // j per split (12*60=720 >= 716)
#define NTN 128    // n-tile in xg2
#define NP 768     // padded n for parts
#define NI4 17     // ceil(DIN/4) i4 slots in w4 layout

__device__ __forceinline__ float sigmf(float x){ return 1.0f/(1.0f+__expf(-x)); }

// ---------------- emb precompute + cur0 ----------------
__global__ void k_emb(const float* __restrict__ src, const float* __restrict__ ne,
                      const float* __restrict__ te, const float* __restrict__ de,
                      float* __restrict__ emb, float* __restrict__ cur){
  int idx = blockIdx.x*256 + threadIdx.x;
  if (idx >= BB*TT*NN) return;
  int n = idx % NN; int t = (idx/NN) % TT; int b = idx/(NN*TT);
  const float* s = src + (size_t)idx*3;
  float x = s[0];
  int ti = (int)(s[1]*288.0f);
  int di = (int)(s[2]);
  size_t eo = ((size_t)b*TT + t)*NN*EE + (size_t)n*EE;
  #pragma unroll
  for (int e=0;e<EE;e++)
    emb[eo+e] = ne[n*EE+e]*te[ti*EE+e]*de[di*EE+e];
  cur[((size_t)t*BB + b)*NN + n] = x;   // cur[0][t][b][n]
}

// ---------------- per-layer w4[n][k][i4][O][4] = static@wp (gate+update in one) ----------------
__global__ __launch_bounds__(256) void k_prep_w4m(
    const float* __restrict__ ne, const float* __restrict__ wp_g,
    const float* __restrict__ wp_u, float* __restrict__ wg4,
    float* __restrict__ wu4)
{
  __shared__ float wps[EE*4*OG];
  int which = blockIdx.z;
  const float* wp = which ? wp_u : wp_g;
  float* w4 = which ? wu4 : wg4;
  int O = which ? OU : OG;
  int ki4 = blockIdx.x;          // 0..33 : k*17+i4
  int nq  = blockIdx.y;          // 0..3
  int k = ki4/NI4, i4 = ki4 - k*NI4;
  int tid = threadIdx.x;
  for (int idx=tid; idx<EE*4*O; idx+=256){
    int e = idx/(4*O); int rem = idx - e*4*O; int sub = rem/O; int o = rem - sub*O;
    int i = i4*4 + sub;
    wps[idx] = (i<DIN) ? wp[(((size_t)e*2+k)*DIN+i)*O + o] : 0.f;
  }
  __syncthreads();
  int NG = 256/O;
  int o = tid & (O-1), ng = tid / O;
  int n1 = nq*179, n2 = min(NN, n1+179);
  for (int n = n1+ng; n < n2; n += NG){
    float4 a = {0.f,0.f,0.f,0.f};
    #pragma unroll
    for (int e=0;e<EE;e++){
      float nef = ne[n*EE+e];
      a.x += nef*wps[e*4*O + 0*O + o];
      a.y += nef*wps[e*4*O + 1*O + o];
      a.z += nef*wps[e*4*O + 2*O + o];
      a.w += nef*wps[e*4*O + 3*O + o];
    }
    ((float4*)w4)[((size_t)(n*2+k)*NI4 + i4)*O + o] = a;
  }
}

// ---------------- per-layer misc: biases + h=0 + xs/nv init ----------------
__global__ void k_misc(const float* __restrict__ ne,
                       const float* __restrict__ bp_g, const float* __restrict__ bp_u,
                       float* __restrict__ bg, float* __restrict__ bu,
                       float* __restrict__ h, const float* __restrict__ cur_c,
                       const float* __restrict__ f1W, const float* __restrict__ f1b,
                       const float* __restrict__ f2W, const float* __restrict__ f2b,
                       const float* __restrict__ f3W, const float* __restrict__ f3b,
                       const float* __restrict__ emb,
                       float* __restrict__ xsg, float* __restrict__ nv){
  int mt = blockIdx.x*256 + threadIdx.x;
  int MT = gridDim.x*256;
  for (int i=mt; i<BB*NN*HH; i+=MT) h[i] = 0.f;
  for (int i=mt; i<NN*OG; i+=MT){
    int o=i&(OG-1), n=i>>7; float a=0.f;
    #pragma unroll
    for (int e=0;e<EE;e++) a += ne[n*EE+e]*bp_g[e*OG+o];
    bg[i]=a;
  }
  for (int i=mt; i<NN*OU; i+=MT){
    int o=i&(OU-1), n=i>>6; float a=0.f;
    #pragma unroll
    for (int e=0;e<EE;e++) a += ne[n*EE+e]*bp_u[e*OU+o];
    bu[i]=a;
  }
  for (int idx=mt; idx<BB*NN; idx+=MT){
    int b=idx/NN, n=idx-b*NN;
    float x = cur_c[(size_t)b*NN + n];   // t = 0
    float* xr = xsg + (size_t)idx*XSP;
    xr[0]=x;
    #pragma unroll
    for (int i2=1;i2<XSP;i2++) xr[i2]=0.f;
    float h1[16];
    #pragma unroll
    for (int k=0;k<16;k++) h1[k]=sigmf(f1b[k]+f1W[k*DIN]*x);
    float h2[2];
    #pragma unroll
    for (int k=0;k<2;k++){
      float s=f2b[k];
      #pragma unroll
      for (int q=0;q<16;q++) s+=f2W[k*16+q]*h1[q];
      h2[k]=sigmf(s);
    }
    #pragma unroll
    for (int e=0;e<EE;e++){
      float xe=f3b[e]+f3W[e*2]*h2[0]+f3W[e*2+1]*h2[1];
      nv[(size_t)idx*EE+e]=tanhf(emb[(((size_t)b*TT+0)*NN+n)*EE+e]*xe);
    }
  }
}

// ---------------- fused d + xg2 gemm (G on the fly), 128n x 64i tile ----------------
// grid (nc=6, js=12, b=8); parts[js][b][n][i<=64], d[b][j] (redundant-identical across nc)
__global__ __launch_bounds__(256) void k_xg2d(
    const float* __restrict__ nv, const float* __restrict__ xs,
    float* __restrict__ parts, float* __restrict__ dout)
{
  __shared__ float a_nv[NTN*11];                 // 5.6 KB
  __shared__ float b_nv[64*11];                  // 2.8 KB
  __shared__ float dls[64];
  __shared__ __align__(16) float big[12800];     // 51.2 KB: nvs(7160) then xss|gs
  float* nvs = big;                              // [716][10]
  float (*xss)[XSP] = (float(*)[XSP])big;        // [64][68] = 4352
  float (*gs)[NTN+4] = (float(*)[NTN+4])(big + 4352); // [64][132] = 8448

  int nc = blockIdx.x, js = blockIdx.y, b = blockIdx.z;
  int tid = threadIdx.x;
  int n0 = nc*NTN;
  int j0 = js*JRX;
  int jend = min(NN, j0+JRX);
  int cnt = jend - j0;                // 60 or 56
  // ---- P0: stage full nv[b] into nvs (coalesced float4)
  {
    const float4* src4 = (const float4*)(nv + (size_t)b*NN*EE);
    for (int i=tid; i<NN*EE/4; i+=256) ((float4*)nvs)[i] = src4[i];
  }
  __syncthreads();
  // ---- P1: copy a_nv/b_nv slices (LDS->LDS) + register-blocked d for this j-range
  for (int idx=tid; idx<NTN*EE; idx+=256){
    int r = idx/EE, e = idx - r*EE;
    int n = n0 + r;
    a_nv[r*11+e] = (n<NN) ? nvs[n*EE+e] : 0.f;
  }
  for (int idx=tid; idx<64*EE; idx+=256){
    int r = idx/EE, e = idx - r*EE;
    b_nv[r*11+e] = (r<cnt) ? nvs[(j0+r)*EE+e] : 0.f;
  }
  {
    int jg = tid>>4, ns = tid&15;
    float bv[4][EE];
    #pragma unroll
    for (int r=0;r<4;r++){
      int jr = jg*4+r;
      bool ok = (jr < cnt);
      #pragma unroll
      for (int e=0;e<EE;e++) bv[r][e] = ok ? nvs[(j0+jr)*EE+e] : 0.f;
    }
    float sums[4]={0.f,0.f,0.f,0.f};
    for (int n=ns; n<NN; n+=16){
      float av[EE];
      #pragma unroll
      for (int e=0;e<EE;e++) av[e] = nvs[n*EE+e];
      #pragma unroll
      for (int r=0;r<4;r++){
        float s=0.f;
        #pragma unroll
        for (int e=0;e<EE;e++) s += bv[r][e]*av[e];
        sums[r] += fmaxf(s,0.f);
      }
    }
    #pragma unroll
    for (int r=0;r<4;r++){
      float s = sums[r];
      s += __shfl_xor(s,1,64); s += __shfl_xor(s,2,64);
      s += __shfl_xor(s,4,64); s += __shfl_xor(s,8,64);
      sums[r] = s;
    }
    if (ns==0){
      #pragma unroll
      for (int r=0;r<4;r++){
        int jr = jg*4+r;
        if (jr < cnt){
          float dv = rsqrtf(sums[r]);
          dls[jr] = dv;
          dout[b*NN + j0 + jr] = dv;
        }
      }
    }
  }
  __syncthreads();
  // ---- P2: xss staging (d_j-scaled) + G tile compute (overwrites nvs region)
  for (int idx=tid; idx<64*64; idx+=256){
    int r = idx>>6, ii = idx&63;
    xss[r][ii] = (r<cnt) ? dls[r]*xs[((size_t)b*NN+j0+r)*XSP+ii] : 0.f;
  }
  if (tid < 64)
    xss[tid][64] = (tid<cnt) ? dls[tid]*xs[((size_t)b*NN+j0+tid)*XSP+64] : 0.f;
  {
    int jg = tid>>4, ng3 = tid&15;
    float g[4][8];
    #pragma unroll
    for (int r=0;r<4;r++)
      #pragma unroll
      for (int s2=0;s2<8;s2++) g[r][s2]=0.f;
    #pragma unroll
    for (int e=0;e<EE;e++){
      float bv[4], av[8];
      #pragma unroll
      for (int r=0;r<4;r++) bv[r] = b_nv[(jg*4+r)*11+e];
      #pragma unroll
      for (int s2=0;s2<8;s2++) av[s2] = a_nv[(ng3*8+s2)*11+e];
      #pragma unroll
      for (int r=0;r<4;r++)
        #pragma unroll
        for (int s2=0;s2<8;s2++) g[r][s2] += bv[r]*av[s2];
    }
    #pragma unroll
    for (int r=0;r<4;r++){
      float4 v0 = { fmaxf(g[r][0],0.f), fmaxf(g[r][1],0.f),
                    fmaxf(g[r][2],0.f), fmaxf(g[r][3],0.f) };
      float4 v1 = { fmaxf(g[r][4],0.f), fmaxf(g[r][5],0.f),
                    fmaxf(g[r][6],0.f), fmaxf(g[r][7],0.f) };
      *(float4*)&gs[jg*4+r][ng3*8]   = v0;
      *(float4*)&gs[jg*4+r][ng3*8+4] = v1;
    }
  }
  __syncthreads();
  // ---- P3: main accumulation (ng: 4 n's, ig: 8 i's)
  int ng = tid >> 3, ig = tid & 7;
  float acc[4][8];
  #pragma unroll
  for (int r=0;r<4;r++)
    #pragma unroll
    for (int s2=0;s2<8;s2++) acc[r][s2]=0.f;
  for (int jj=0; jj<cnt; ++jj){
    float4 g4  = *(const float4*)&gs[jj][ng*4];
    float4 x4a = *(const float4*)&xss[jj][ig*8];
    float4 x4b = *(const float4*)&xss[jj][ig*8+4];
    float gr[4] = {g4.x, g4.y, g4.z, g4.w};
    float xr[8] = {x4a.x,x4a.y,x4a.z,x4a.w, x4b.x,x4b.y,x4b.z,x4b.w};
    #pragma unroll
    for (int r=0;r<4;r++)
      #pragma unroll
      for (int s2=0;s2<8;s2++) acc[r][s2] += gr[r]*xr[s2];
  }
  #pragma unroll
  for (int r=0;r<4;r++){
    int n = n0 + ng*4 + r;    // < NP always
    float4 v0 = { acc[r][0], acc[r][1], acc[r][2], acc[r][3] };
    float4 v1 = { acc[r][4], acc[r][5], acc[r][6], acc[r][7] };
    size_t base = (((size_t)js*BB+b)*NP+n)*XSP;
    *(float4*)&parts[base + ig*8]     = v0;
    *(float4*)&parts[base + ig*8 + 4] = v1;
  }
  if (tid < NTN){
    float s = 0.f;
    for (int jj=0; jj<cnt; ++jj) s += gs[jj][tid]*xss[jj][64];
    parts[(((size_t)js*BB+b)*NP + n0+tid)*XSP + 64] = s;
  }
}

// ---------------- gate transform (w4 float4 layout, reg-capped) ----------------
__global__ __launch_bounds__(256, 4) void k_tr_gate(
    const float* __restrict__ wg, const float* __restrict__ bg,
    const float* __restrict__ parts, const float* __restrict__ d,
    const float* __restrict__ xsg,
    const float* __restrict__ cur_ct, const float* __restrict__ h,
    const float* __restrict__ emb, int t,
    const float* __restrict__ f1W, const float* __restrict__ f1b,
    const float* __restrict__ f2W, const float* __restrict__ f2b,
    const float* __restrict__ f3W, const float* __restrict__ f3b,
    float* __restrict__ rbuf, float* __restrict__ xsu, float* __restrict__ nv)
{
  __shared__ float xg2s[BB][XSP];
  __shared__ float xss[BB][XSP];
  __shared__ float cs[BB][DIN];
  __shared__ float h1s[BB][16];
  __shared__ float h2s[BB][2];
  int n = blockIdx.x;
  int tid = threadIdx.x;
  for (int idx=tid; idx<BB*XSP; idx+=256){
    int b = idx/XSP, i = idx - b*XSP;
    float s = 0.f;
    if (i < 65){
      #pragma unroll
      for (int js2=0; js2<JS; js2++)
        s += parts[(((size_t)js2*BB+b)*NP+n)*XSP + i];
      s *= d[b*NN+n];
    }
    xg2s[b][i] = s;
  }
  for (int idx=tid; idx<BB*XSP; idx+=256){
    int b = idx/XSP, i = idx - b*XSP;
    xss[b][i] = (i<65) ? xsg[((size_t)b*NN+n)*XSP + i] : 0.f;
  }
  __syncthreads();
  {
    int o = tid & 127, half = tid >> 7;
    const float4* w0p = (const float4*)wg + ((size_t)n*2+0)*NI4*OG + o;
    const float4* w1p = w0p + (size_t)NI4*OG;
    float bgv = bg[n*OG+o];
    float acc[4]; acc[0]=bgv; acc[1]=bgv; acc[2]=bgv; acc[3]=bgv;
    #pragma unroll 2
    for (int i4=0;i4<NI4;i4++){
      float4 w0 = w0p[(size_t)i4*OG];
      float4 w1 = w1p[(size_t)i4*OG];
      int i = i4*4;
      #pragma unroll
      for (int bb=0;bb<4;bb++){
        int b = 2*bb+half;
        acc[bb] += xss[b][i]*w0.x + xss[b][i+1]*w0.y
                 + xss[b][i+2]*w0.z + xss[b][i+3]*w0.w
                 + xg2s[b][i]*w1.x + xg2s[b][i+1]*w1.y
                 + xg2s[b][i+2]*w1.z + xg2s[b][i+3]*w1.w;
      }
    }
    #pragma unroll
    for (int bb=0;bb<4;bb++){
      int b = 2*bb+half;
      float v = sigmf(acc[bb]);
      if (o < 64){
        float cv = v * h[((size_t)b*NN+n)*HH + o];
        xsu[((size_t)b*NN+n)*XSP + 1 + o] = cv;
        cs[b][1+o] = cv;
      } else {
        rbuf[((size_t)b*NN+n)*HH + (o-64)] = v;
      }
    }
    if (o == 64){
      #pragma unroll
      for (int bb=0;bb<4;bb++){
        int b = 2*bb+half;
        float x = cur_ct[(size_t)b*NN+n];
        cs[b][0] = x;
        xsu[((size_t)b*NN+n)*XSP] = x;
      }
    }
  }
  __syncthreads();
  if (tid < BB*16){
    int b=tid>>4, k=tid&15;
    const float* wr = f1W + k*DIN;
    float s = f1b[k];
    #pragma unroll
    for (int i=0;i<DIN;i++) s += cs[b][i]*wr[i];
    h1s[b][k] = sigmf(s);
  }
  __syncthreads();
  if (tid < BB*2){
    int b=tid>>1, k=tid&1;
    float s = f2b[k];
    #pragma unroll
    for (int q2=0;q2<16;q2++) s += h1s[b][q2]*f2W[k*16+q2];
    h2s[b][k] = sigmf(s);
  }
  __syncthreads();
  if (tid < BB*EE){
    int b=tid/EE, e=tid-b*EE;
    float xe = f3b[e] + f3W[e*2]*h2s[b][0] + f3W[e*2+1]*h2s[b][1];
    nv[((size_t)b*NN+n)*EE+e] = tanhf(emb[(((size_t)b*TT+t)*NN+n)*EE+e]*xe);
  }
}

// ---------------- update transform (w4 float4 layout, reg-capped) ----------------
__global__ __launch_bounds__(256, 4) void k_tr_upd(
    const float* __restrict__ wu, const float* __restrict__ bu,
    const float* __restrict__ parts, const float* __restrict__ d,
    const float* __restrict__ xsu,
    const float* __restrict__ rbuf, float* __restrict__ h,
    float* __restrict__ cur, int c, int t,
    const float* __restrict__ emb,
    const float* __restrict__ f1W, const float* __restrict__ f1b,
    const float* __restrict__ f2W, const float* __restrict__ f2b,
    const float* __restrict__ f3W, const float* __restrict__ f3b,
    float* __restrict__ xsg, float* __restrict__ nv,
    const float* __restrict__ predW, const float* __restrict__ predB,
    const float* __restrict__ skipW, const float* __restrict__ skipB,
    float* __restrict__ out)
{
  __shared__ float xg2s[BB][XSP];
  __shared__ float xss[BB][XSP];
  __shared__ float hs[BB][HH];
  __shared__ float h1s[BB][16];
  __shared__ float h2s[BB][2];
  __shared__ float xns[BB];
  int n = blockIdx.x;
  int tid = threadIdx.x;
  for (int idx=tid; idx<BB*XSP; idx+=256){
    int b = idx/XSP, i = idx - b*XSP;
    float s = 0.f;
    if (i < 65){
      #pragma unroll
      for (int js2=0; js2<JS; js2++)
        s += parts[(((size_t)js2*BB+b)*NP+n)*XSP + i];
      s *= d[b*NN+n];
    }
    xg2s[b][i] = s;
  }
  for (int idx=tid; idx<BB*XSP; idx+=256){
    int b = idx/XSP, i = idx - b*XSP;
    xss[b][i] = (i<65) ? xsu[((size_t)b*NN+n)*XSP + i] : 0.f;
  }
  __syncthreads();
  {
    int o = tid & 63, grp = tid >> 6;
    const float4* w0p = (const float4*)wu + ((size_t)n*2+0)*NI4*OU + o;
    const float4* w1p = w0p + (size_t)NI4*OU;
    float acc[2];
    acc[0] = bu[n*OU+o]; acc[1] = acc[0];
    #pragma unroll 2
    for (int i4=0;i4<NI4;i4++){
      float4 w0 = w0p[(size_t)i4*OU];
      float4 w1 = w1p[(size_t)i4*OU];
      int i = i4*4;
      #pragma unroll
      for (int bb=0;bb<2;bb++){
        int b = grp + 4*bb;
        acc[bb] += xss[b][i]*w0.x + xss[b][i+1]*w0.y
                 + xss[b][i+2]*w0.z + xss[b][i+3]*w0.w
                 + xg2s[b][i]*w1.x + xg2s[b][i+1]*w1.y
                 + xg2s[b][i+2]*w1.z + xg2s[b][i+3]*w1.w;
      }
    }
    #pragma unroll
    for (int bb=0;bb<2;bb++){
      int b = grp + 4*bb;
      float hc = tanhf(acc[bb]);
      float r = rbuf[((size_t)b*NN+n)*HH+o];
      float hold = h[((size_t)b*NN+n)*HH+o];
      float hn = r*hold + (1.f-r)*hc;
      h[((size_t)b*NN+n)*HH+o] = hn;
      hs[b][o] = hn;
    }
  }
  __syncthreads();
  if (t < TT-1){
    if (tid < BB){
      float x = cur[(((size_t)c*TT + (t+1))*BB + tid)*NN + n];
      xns[tid] = x;
      xsg[((size_t)tid*NN+n)*XSP] = x;
    }
    for (int idx=tid; idx<BB*HH; idx+=256){
      int b = idx>>6, oo = idx&63;
      xsg[((size_t)b*NN+n)*XSP + 1 + oo] = hs[b][oo];
    }
    __syncthreads();
    if (tid < BB*16){
      int b=tid>>4, k=tid&15;
      const float* wr = f1W + k*DIN;
      float s = f1b[k] + wr[0]*xns[b];
      #pragma unroll
      for (int oo=0;oo<HH;oo++) s += hs[b][oo]*wr[1+oo];
      h1s[b][k] = sigmf(s);
    }
    __syncthreads();
    if (tid < BB*2){
      int b=tid>>1, k=tid&1;
      float s = f2b[k];
      #pragma unroll
      for (int q2=0;q2<16;q2++) s += h1s[b][q2]*f2W[k*16+q2];
      h2s[b][k] = sigmf(s);
    }
    __syncthreads();
    if (tid < BB*EE){
      int b=tid/EE, e=tid-b*EE;
      float xe = f3b[e] + f3W[e*2]*h2s[b][0] + f3W[e*2+1]*h2s[b][1];
      nv[((size_t)b*NN+n)*EE+e] =
        tanhf(emb[(((size_t)b*TT+(t+1))*NN+n)*EE+e]*xe);
    }
  } else {
    if (tid < BB*TT){
      int b = tid/TT, ot = tid - b*TT;
      const float* pw = predW + ((size_t)c*TT + ot)*HH;
      float pv = predB[c*TT+ot];
      #pragma unroll
      for (int q2=0;q2<HH;q2++) pv += hs[b][q2]*pw[q2];
      size_t oi = ((size_t)b*TT+ot)*NN + n;
      if (c == 0){
        out[oi] = pv;
        const float* sw = skipW + (size_t)ot*HH;
        float sk = skipB[ot];
        #pragma unroll
        for (int q2=0;q2<HH;q2++) sk += hs[b][q2]*sw[q2];
        cur[(((size_t)TT+ot)*BB + b)*NN + n] =
            cur[((size_t)ot*BB + b)*NN + n] - sk;
      } else {
        out[oi] += pv;
      }
    }
  }
}

extern "C" void kernel_launch(void* const* d_in, const int* in_sizes, int n_in,
                              void* d_out, int out_size, void* d_ws, size_t ws_size,
                              hipStream_t stream){
  const float* src  = (const float*)d_in[0];
  const float* ne   = (const float*)d_in[1];
  const float* te   = (const float*)d_in[2];
  const float* de   = (const float*)d_in[3];
  const float* wp_g = (const float*)d_in[4];
  const float* bp_g = (const float*)d_in[5];
  const float* f1W_g= (const float*)d_in[6];
  const float* f1b_g= (const float*)d_in[7];
  const float* f2W_g= (const float*)d_in[8];
  const float* f2b_g= (const float*)d_in[9];
  const float* f3W_g= (const float*)d_in[10];
  const float* f3b_g= (const float*)d_in[11];
  const float* wp_u = (const float*)d_in[12];
  const float* bp_u = (const float*)d_in[13];
  const float* f1W_u= (const float*)d_in[14];
  const float* f1b_u= (const float*)d_in[15];
  const float* f2W_u= (const float*)d_in[16];
  const float* f2b_u= (const float*)d_in[17];
  const float* f3W_u= (const float*)d_in[18];
  const float* f3b_u= (const float*)d_in[19];
  const float* predW= (const float*)d_in[20];
  const float* predB= (const float*)d_in[21];
  const float* skipW= (const float*)d_in[22];
  const float* skipB= (const float*)d_in[23];

  float* ws   = (float*)d_ws;
  float* emb  = ws;
  float* cur  = emb  + (size_t)BB*TT*NN*EE;
  float* wg   = cur  + (size_t)2*TT*BB*NN;
  float* bg   = wg   + (size_t)NN*2*NI4*OG*4;
  float* wu   = bg   + (size_t)NN*OG;
  float* bu   = wu   + (size_t)NN*2*NI4*OU*4;
  float* h    = bu   + (size_t)NN*OU;
  float* xsg  = h    + (size_t)BB*NN*HH;
  float* xsu  = xsg  + (size_t)BB*NN*XSP;
  float* nv   = xsu  + (size_t)BB*NN*XSP;
  float* dbuf = nv   + (size_t)BB*NN*EE;
  float* parts= dbuf + (size_t)BB*NN;
  float* rbuf = parts+ (size_t)JS*BB*NP*XSP;
  float* outp = (float*)d_out;

  k_emb<<<(BB*TT*NN+255)/256, 256, 0, stream>>>(src, ne, te, de, emb, cur);

  for (int c=0;c<2;c++){
    k_prep_w4m<<<dim3(2*NI4,4,2),256,0,stream>>>(ne,
        wp_g + (size_t)c*EE*2*DIN*OG, wp_u + (size_t)c*EE*2*DIN*OU, wg, wu);
    k_misc<<<1024,256,0,stream>>>(ne, bp_g + (size_t)c*EE*OG, bp_u + (size_t)c*EE*OU,
        bg, bu, h, cur + (size_t)c*TT*BB*NN,
        f1W_g + c*16*DIN, f1b_g + c*16, f2W_g + c*32, f2b_g + c*2,
        f3W_g + c*EE*2, f3b_g + c*EE, emb, xsg, nv);
    for (int t=0;t<TT;t++){
      k_xg2d<<<dim3(6,JS,BB),256,0,stream>>>(nv, xsg, parts, dbuf);
      k_tr_gate<<<NN,256,0,stream>>>(wg, bg, parts, dbuf, xsg,
          cur + ((size_t)c*TT+t)*BB*NN, h, emb, t,
          f1W_u + c*16*DIN, f1b_u + c*16, f2W_u + c*32, f2b_u + c*2,
          f3W_u + c*EE*2, f3b_u + c*EE, rbuf, xsu, nv);
      k_xg2d<<<dim3(6,JS,BB),256,0,stream>>>(nv, xsu, parts, dbuf);
      k_tr_upd<<<NN,256,0,stream>>>(wu, bu, parts, dbuf, xsu, rbuf, h,
          cur, c, t, emb,
          f1W_g + c*16*DIN, f1b_g + c*16, f2W_g + c*32, f2b_g + c*2,
          f3W_g + c*EE*2, f3b_g + c*EE,
          xsg, nv, predW, predB, skipW, skipB, outp);
    }
  }
}

// Round 8
// 2967.572 us; speedup vs baseline: 1.4350x; 1.0841x over previous
//
#include <hip/hip_runtime.h>
#include <math.h>

#define BB 8
#define TT 12
#define NN 716
#define EE 10
#define HH 64
#define DIN 65
#define OG 128
#define OU 64
#define XSP 68     // padded xs / parts row stride
#define JS 32      // j-split for xg2 gemm
#define JRX 23     // j per split (32*23=736 >= 716)
#define NTN 128    // n-tile in xg2
#define NP 768     // padded n for parts
#define NI4 17     // ceil(DIN/4) i4 slots in w4 layout
#define NVP 12     // padded nv row stride (48B, 16B-aligned)

__device__ __forceinline__ float sigmf(float x){ return 1.0f/(1.0f+__expf(-x)); }

// ---------------- emb precompute + cur0 ----------------
__global__ void k_emb(const float* __restrict__ src, const float* __restrict__ ne,
                      const float* __restrict__ te, const float* __restrict__ de,
                      float* __restrict__ emb, float* __restrict__ cur){
  int idx = blockIdx.x*256 + threadIdx.x;
  if (idx >= BB*TT*NN) return;
  int n = idx % NN; int t = (idx/NN) % TT; int b = idx/(NN*TT);
  const float* s = src + (size_t)idx*3;
  float x = s[0];
  int ti = (int)(s[1]*288.0f);
  int di = (int)(s[2]);
  size_t eo = ((size_t)b*TT + t)*NN*EE + (size_t)n*EE;
  #pragma unroll
  for (int e=0;e<EE;e++)
    emb[eo+e] = ne[n*EE+e]*te[ti*EE+e]*de[di*EE+e];
  cur[((size_t)t*BB + b)*NN + n] = x;   // cur[0][t][b][n]
}

// ---------------- per-layer w4[n][k][i4][O][4] = static@wp (gate+update in one) ----------------
__global__ __launch_bounds__(256) void k_prep_w4m(
    const float* __restrict__ ne, const float* __restrict__ wp_g,
    const float* __restrict__ wp_u, float* __restrict__ wg4,
    float* __restrict__ wu4)
{
  __shared__ float wps[EE*4*OG];
  int which = blockIdx.z;
  const float* wp = which ? wp_u : wp_g;
  float* w4 = which ? wu4 : wg4;
  int O = which ? OU : OG;
  int ki4 = blockIdx.x;          // 0..33 : k*17+i4
  int nq  = blockIdx.y;          // 0..3
  int k = ki4/NI4, i4 = ki4 - k*NI4;
  int tid = threadIdx.x;
  for (int idx=tid; idx<EE*4*O; idx+=256){
    int e = idx/(4*O); int rem = idx - e*4*O; int sub = rem/O; int o = rem - sub*O;
    int i = i4*4 + sub;
    wps[idx] = (i<DIN) ? wp[(((size_t)e*2+k)*DIN+i)*O + o] : 0.f;
  }
  __syncthreads();
  int NG = 256/O;
  int o = tid & (O-1), ng = tid / O;
  int n1 = nq*179, n2 = min(NN, n1+179);
  for (int n = n1+ng; n < n2; n += NG){
    float4 a = {0.f,0.f,0.f,0.f};
    #pragma unroll
    for (int e=0;e<EE;e++){
      float nef = ne[n*EE+e];
      a.x += nef*wps[e*4*O + 0*O + o];
      a.y += nef*wps[e*4*O + 1*O + o];
      a.z += nef*wps[e*4*O + 2*O + o];
      a.w += nef*wps[e*4*O + 3*O + o];
    }
    ((float4*)w4)[((size_t)(n*2+k)*NI4 + i4)*O + o] = a;
  }
}

// ---------------- per-layer misc: biases + h=0 + xs/nv init ----------------
__global__ void k_misc(const float* __restrict__ ne,
                       const float* __restrict__ bp_g, const float* __restrict__ bp_u,
                       float* __restrict__ bg, float* __restrict__ bu,
                       float* __restrict__ h, const float* __restrict__ cur_c,
                       const float* __restrict__ f1W, const float* __restrict__ f1b,
                       const float* __restrict__ f2W, const float* __restrict__ f2b,
                       const float* __restrict__ f3W, const float* __restrict__ f3b,
                       const float* __restrict__ emb,
                       float* __restrict__ xsg, float* __restrict__ nv){
  int mt = blockIdx.x*256 + threadIdx.x;
  int MT = gridDim.x*256;
  for (int i=mt; i<BB*NN*HH; i+=MT) h[i] = 0.f;
  for (int i=mt; i<NN*OG; i+=MT){
    int o=i&(OG-1), n=i>>7; float a=0.f;
    #pragma unroll
    for (int e=0;e<EE;e++) a += ne[n*EE+e]*bp_g[e*OG+o];
    bg[i]=a;
  }
  for (int i=mt; i<NN*OU; i+=MT){
    int o=i&(OU-1), n=i>>6; float a=0.f;
    #pragma unroll
    for (int e=0;e<EE;e++) a += ne[n*EE+e]*bp_u[e*OU+o];
    bu[i]=a;
  }
  for (int idx=mt; idx<BB*NN; idx+=MT){
    int b=idx/NN, n=idx-b*NN;
    float x = cur_c[(size_t)b*NN + n];   // t = 0
    float* xr = xsg + (size_t)idx*XSP;
    xr[0]=x;
    #pragma unroll
    for (int i2=1;i2<XSP;i2++) xr[i2]=0.f;
    float h1[16];
    #pragma unroll
    for (int k=0;k<16;k++) h1[k]=sigmf(f1b[k]+f1W[k*DIN]*x);
    float h2[2];
    #pragma unroll
    for (int k=0;k<2;k++){
      float s=f2b[k];
      #pragma unroll
      for (int q=0;q<16;q++) s+=f2W[k*16+q]*h1[q];
      h2[k]=sigmf(s);
    }
    #pragma unroll
    for (int e=0;e<EE;e++){
      float xe=f3b[e]+f3W[e*2]*h2[0]+f3W[e*2+1]*h2[1];
      nv[(size_t)idx*EE+e]=tanhf(emb[(((size_t)b*TT+0)*NN+n)*EE+e]*xe);
    }
  }
}

// ---------------- fused d + xg2 gemm, 1-round grid, nc looped in-block ----------------
// grid (js=32, b=8) = 256 blocks; parts[js][b][n][i<=64], d[b][j] computed once per j
__global__ __launch_bounds__(256) void k_xg2d(
    const float* __restrict__ nv, const float* __restrict__ xs,
    float* __restrict__ parts, float* __restrict__ dout)
{
  __shared__ __align__(16) float nvs[NN*NVP];      // 34368 B, row stride 12
  __shared__ __align__(16) float xss[32][XSP];     // 8704 B
  __shared__ __align__(16) float gs[32][NTN+4];    // 16896 B
  __shared__ float dls[32];
  int js = blockIdx.x, b = blockIdx.y;
  int tid = threadIdx.x;
  int j0 = js*JRX;
  int cnt = NN - j0; if (cnt > JRX) cnt = JRX;     // 23 (or 3 for js=31)
  // ---- P0: stage nv[b] -> nvs (stride 12)
  {
    const float* nvb = nv + (size_t)b*NN*EE;
    for (int idx=tid; idx<NN*EE; idx+=256){
      int n = idx/10, e = idx - n*10;
      nvs[n*NVP+e] = nvb[idx];
    }
  }
  __syncthreads();
  // ---- P1: d for this j-range (once per j across whole dispatch)
  int jg = tid>>5, ns = tid&31;     // 8 groups x 4 j-slots = 32 slots >= 23
  float bv[4][EE];
  #pragma unroll
  for (int r=0;r<4;r++){
    int jr = jg*4+r;
    if (jr < cnt){
      const float* bp2 = &nvs[(j0+jr)*NVP];
      float4 b0 = *(const float4*)bp2;
      float4 b1 = *(const float4*)(bp2+4);
      float2 b2 = *(const float2*)(bp2+8);
      bv[r][0]=b0.x; bv[r][1]=b0.y; bv[r][2]=b0.z; bv[r][3]=b0.w;
      bv[r][4]=b1.x; bv[r][5]=b1.y; bv[r][6]=b1.z; bv[r][7]=b1.w;
      bv[r][8]=b2.x; bv[r][9]=b2.y;
    } else {
      #pragma unroll
      for (int e=0;e<EE;e++) bv[r][e]=0.f;
    }
  }
  {
    float sums[4]={0.f,0.f,0.f,0.f};
    for (int n=ns; n<NN; n+=32){
      const float* ap = &nvs[n*NVP];
      float4 a0 = *(const float4*)ap;
      float4 a1 = *(const float4*)(ap+4);
      float2 a2 = *(const float2*)(ap+8);
      float av[10] = {a0.x,a0.y,a0.z,a0.w,a1.x,a1.y,a1.z,a1.w,a2.x,a2.y};
      #pragma unroll
      for (int r=0;r<4;r++){
        float s=0.f;
        #pragma unroll
        for (int e=0;e<EE;e++) s += bv[r][e]*av[e];
        sums[r] += fmaxf(s,0.f);
      }
    }
    #pragma unroll
    for (int r=0;r<4;r++){
      float s = sums[r];
      s += __shfl_xor(s,1,64); s += __shfl_xor(s,2,64);
      s += __shfl_xor(s,4,64); s += __shfl_xor(s,8,64);
      s += __shfl_xor(s,16,64);
      sums[r] = s;
    }
    if (ns==0){
      #pragma unroll
      for (int r=0;r<4;r++){
        int jr = jg*4+r;
        if (jr < cnt){
          float dv = rsqrtf(sums[r]);
          dls[jr] = dv;
          dout[b*NN + j0 + jr] = dv;
        }
      }
    }
  }
  __syncthreads();   // dls ready
  // ---- P2: stage d_j-scaled xs rows (cols 65..67 zero)
  for (int idx=tid; idx<32*XSP; idx+=256){
    int r = idx/XSP, ii = idx - r*XSP;
    float v = 0.f;
    if (r < cnt && ii <= 64)
      v = dls[r]*xs[((size_t)b*NN+j0+r)*XSP + ii];
    xss[r][ii] = v;
  }
  // ---- P3: loop n-tiles; G-tile + acc per nc
  int ng = tid >> 3, ig = tid & 7;  // acc: 4 n's at ng*4, 8 i's at ig*8
  int ng4 = tid & 31;               // G: 4 n's at ng4*4 (jg reused for 4 j's)
  for (int nc=0; nc<6; ++nc){
    int n0 = nc*NTN;
    // G-tile: thread (jg:4j) x (ng4:4n), bv held in registers
    {
      float g[4][4];
      #pragma unroll
      for (int r=0;r<4;r++){ g[r][0]=0;g[r][1]=0;g[r][2]=0;g[r][3]=0; }
      #pragma unroll
      for (int s2=0;s2<4;s2++){
        int n = n0 + ng4*4 + s2;
        if (n < NN){
          const float* ap = &nvs[n*NVP];
          float4 a0 = *(const float4*)ap;
          float4 a1 = *(const float4*)(ap+4);
          float2 a2 = *(const float2*)(ap+8);
          float av[10] = {a0.x,a0.y,a0.z,a0.w,a1.x,a1.y,a1.z,a1.w,a2.x,a2.y};
          #pragma unroll
          for (int r=0;r<4;r++){
            float s=0.f;
            #pragma unroll
            for (int e=0;e<EE;e++) s += bv[r][e]*av[e];
            g[r][s2] = s;
          }
        }
      }
      #pragma unroll
      for (int r=0;r<4;r++){
        float4 v = { fmaxf(g[r][0],0.f), fmaxf(g[r][1],0.f),
                     fmaxf(g[r][2],0.f), fmaxf(g[r][3],0.f) };
        *(float4*)&gs[jg*4+r][ng4*4] = v;
      }
    }
    __syncthreads();   // gs ready (and xss on first iter)
    // acc: 4n x 8i per thread over cnt j's
    {
      float acc[4][8];
      #pragma unroll
      for (int r=0;r<4;r++)
        #pragma unroll
        for (int s2=0;s2<8;s2++) acc[r][s2]=0.f;
      for (int jj=0; jj<cnt; ++jj){
        float4 g4  = *(const float4*)&gs[jj][ng*4];
        float4 x4a = *(const float4*)&xss[jj][ig*8];
        float4 x4b = *(const float4*)&xss[jj][ig*8+4];
        float gr[4] = {g4.x, g4.y, g4.z, g4.w};
        float xr[8] = {x4a.x,x4a.y,x4a.z,x4a.w, x4b.x,x4b.y,x4b.z,x4b.w};
        #pragma unroll
        for (int r=0;r<4;r++)
          #pragma unroll
          for (int s2=0;s2<8;s2++) acc[r][s2] += gr[r]*xr[s2];
      }
      #pragma unroll
      for (int r=0;r<4;r++){
        int n = n0 + ng*4 + r;     // < NP always
        float4 v0 = { acc[r][0], acc[r][1], acc[r][2], acc[r][3] };
        float4 v1 = { acc[r][4], acc[r][5], acc[r][6], acc[r][7] };
        size_t base = (((size_t)js*BB+b)*NP+n)*XSP;
        *(float4*)&parts[base + ig*8]     = v0;
        *(float4*)&parts[base + ig*8 + 4] = v1;
      }
      if (tid < NTN){
        float s = 0.f;
        for (int jj=0; jj<cnt; ++jj) s += gs[jj][tid]*xss[jj][64];
        parts[(((size_t)js*BB+b)*NP + n0+tid)*XSP + 64] = s;
      }
    }
    __syncthreads();   // protect gs rewrite
  }
}

// ---------------- gate transform (w4 float4 layout, reg-capped) ----------------
__global__ __launch_bounds__(256, 4) void k_tr_gate(
    const float* __restrict__ wg, const float* __restrict__ bg,
    const float* __restrict__ parts, const float* __restrict__ d,
    const float* __restrict__ xsg,
    const float* __restrict__ cur_ct, const float* __restrict__ h,
    const float* __restrict__ emb, int t,
    const float* __restrict__ f1W, const float* __restrict__ f1b,
    const float* __restrict__ f2W, const float* __restrict__ f2b,
    const float* __restrict__ f3W, const float* __restrict__ f3b,
    float* __restrict__ rbuf, float* __restrict__ xsu, float* __restrict__ nv)
{
  __shared__ float xg2s[BB][XSP];
  __shared__ float xss[BB][XSP];
  __shared__ float cs[BB][DIN];
  __shared__ float h1s[BB][16];
  __shared__ float h2s[BB][2];
  int n = blockIdx.x;
  int tid = threadIdx.x;
  for (int idx=tid; idx<BB*XSP; idx+=256){
    int b = idx/XSP, i = idx - b*XSP;
    float s = 0.f;
    if (i < 65){
      #pragma unroll 8
      for (int js2=0; js2<JS; js2++)
        s += parts[(((size_t)js2*BB+b)*NP+n)*XSP + i];
      s *= d[b*NN+n];
    }
    xg2s[b][i] = s;
  }
  for (int idx=tid; idx<BB*XSP; idx+=256){
    int b = idx/XSP, i = idx - b*XSP;
    xss[b][i] = (i<65) ? xsg[((size_t)b*NN+n)*XSP + i] : 0.f;
  }
  __syncthreads();
  {
    int o = tid & 127, half = tid >> 7;
    const float4* w0p = (const float4*)wg + ((size_t)n*2+0)*NI4*OG + o;
    const float4* w1p = w0p + (size_t)NI4*OG;
    float bgv = bg[n*OG+o];
    float acc[4]; acc[0]=bgv; acc[1]=bgv; acc[2]=bgv; acc[3]=bgv;
    #pragma unroll 2
    for (int i4=0;i4<NI4;i4++){
      float4 w0 = w0p[(size_t)i4*OG];
      float4 w1 = w1p[(size_t)i4*OG];
      int i = i4*4;
      #pragma unroll
      for (int bb=0;bb<4;bb++){
        int b = 2*bb+half;
        acc[bb] += xss[b][i]*w0.x + xss[b][i+1]*w0.y
                 + xss[b][i+2]*w0.z + xss[b][i+3]*w0.w
                 + xg2s[b][i]*w1.x + xg2s[b][i+1]*w1.y
                 + xg2s[b][i+2]*w1.z + xg2s[b][i+3]*w1.w;
      }
    }
    #pragma unroll
    for (int bb=0;bb<4;bb++){
      int b = 2*bb+half;
      float v = sigmf(acc[bb]);
      if (o < 64){
        float cv = v * h[((size_t)b*NN+n)*HH + o];
        xsu[((size_t)b*NN+n)*XSP + 1 + o] = cv;
        cs[b][1+o] = cv;
      } else {
        rbuf[((size_t)b*NN+n)*HH + (o-64)] = v;
      }
    }
    if (o == 64){
      #pragma unroll
      for (int bb=0;bb<4;bb++){
        int b = 2*bb+half;
        float x = cur_ct[(size_t)b*NN+n];
        cs[b][0] = x;
        xsu[((size_t)b*NN+n)*XSP] = x;
      }
    }
  }
  __syncthreads();
  if (tid < BB*16){
    int b=tid>>4, k=tid&15;
    const float* wr = f1W + k*DIN;
    float s = f1b[k];
    #pragma unroll
    for (int i=0;i<DIN;i++) s += cs[b][i]*wr[i];
    h1s[b][k] = sigmf(s);
  }
  __syncthreads();
  if (tid < BB*2){
    int b=tid>>1, k=tid&1;
    float s = f2b[k];
    #pragma unroll
    for (int q2=0;q2<16;q2++) s += h1s[b][q2]*f2W[k*16+q2];
    h2s[b][k] = sigmf(s);
  }
  __syncthreads();
  if (tid < BB*EE){
    int b=tid/EE, e=tid-b*EE;
    float xe = f3b[e] + f3W[e*2]*h2s[b][0] + f3W[e*2+1]*h2s[b][1];
    nv[((size_t)b*NN+n)*EE+e] = tanhf(emb[(((size_t)b*TT+t)*NN+n)*EE+e]*xe);
  }
}

// ---------------- update transform (w4 float4 layout, reg-capped) ----------------
__global__ __launch_bounds__(256, 4) void k_tr_upd(
    const float* __restrict__ wu, const float* __restrict__ bu,
    const float* __restrict__ parts, const float* __restrict__ d,
    const float* __restrict__ xsu,
    const float* __restrict__ rbuf, float* __restrict__ h,
    float* __restrict__ cur, int c, int t,
    const float* __restrict__ emb,
    const float* __restrict__ f1W, const float* __restrict__ f1b,
    const float* __restrict__ f2W, const float* __restrict__ f2b,
    const float* __restrict__ f3W, const float* __restrict__ f3b,
    float* __restrict__ xsg, float* __restrict__ nv,
    const float* __restrict__ predW, const float* __restrict__ predB,
    const float* __restrict__ skipW, const float* __restrict__ skipB,
    float* __restrict__ out)
{
  __shared__ float xg2s[BB][XSP];
  __shared__ float xss[BB][XSP];
  __shared__ float hs[BB][HH];
  __shared__ float h1s[BB][16];
  __shared__ float h2s[BB][2];
  __shared__ float xns[BB];
  int n = blockIdx.x;
  int tid = threadIdx.x;
  for (int idx=tid; idx<BB*XSP; idx+=256){
    int b = idx/XSP, i = idx - b*XSP;
    float s = 0.f;
    if (i < 65){
      #pragma unroll 8
      for (int js2=0; js2<JS; js2++)
        s += parts[(((size_t)js2*BB+b)*NP+n)*XSP + i];
      s *= d[b*NN+n];
    }
    xg2s[b][i] = s;
  }
  for (int idx=tid; idx<BB*XSP; idx+=256){
    int b = idx/XSP, i = idx - b*XSP;
    xss[b][i] = (i<65) ? xsu[((size_t)b*NN+n)*XSP + i] : 0.f;
  }
  __syncthreads();
  {
    int o = tid & 63, grp = tid >> 6;
    const float4* w0p = (const float4*)wu + ((size_t)n*2+0)*NI4*OU + o;
    const float4* w1p = w0p + (size_t)NI4*OU;
    float acc[2];
    acc[0] = bu[n*OU+o]; acc[1] = acc[0];
    #pragma unroll 2
    for (int i4=0;i4<NI4;i4++){
      float4 w0 = w0p[(size_t)i4*OU];
      float4 w1 = w1p[(size_t)i4*OU];
      int i = i4*4;
      #pragma unroll
      for (int bb=0;bb<2;bb++){
        int b = grp + 4*bb;
        acc[bb] += xss[b][i]*w0.x + xss[b][i+1]*w0.y
                 + xss[b][i+2]*w0.z + xss[b][i+3]*w0.w
                 + xg2s[b][i]*w1.x + xg2s[b][i+1]*w1.y
                 + xg2s[b][i+2]*w1.z + xg2s[b][i+3]*w1.w;
      }
    }
    #pragma unroll
    for (int bb=0;bb<2;bb++){
      int b = grp + 4*bb;
      float hc = tanhf(acc[bb]);
      float r = rbuf[((size_t)b*NN+n)*HH+o];
      float hold = h[((size_t)b*NN+n)*HH+o];
      float hn = r*hold + (1.f-r)*hc;
      h[((size_t)b*NN+n)*HH+o] = hn;
      hs[b][o] = hn;
    }
  }
  __syncthreads();
  if (t < TT-1){
    if (tid < BB){
      float x = cur[(((size_t)c*TT + (t+1))*BB + tid)*NN + n];
      xns[tid] = x;
      xsg[((size_t)tid*NN+n)*XSP] = x;
    }
    for (int idx=tid; idx<BB*HH; idx+=256){
      int b = idx>>6, oo = idx&63;
      xsg[((size_t)b*NN+n)*XSP + 1 + oo] = hs[b][oo];
    }
    __syncthreads();
    if (tid < BB*16){
      int b=tid>>4, k=tid&15;
      const float* wr = f1W + k*DIN;
      float s = f1b[k] + wr[0]*xns[b];
      #pragma unroll
      for (int oo=0;oo<HH;oo++) s += hs[b][oo]*wr[1+oo];
      h1s[b][k] = sigmf(s);
    }
    __syncthreads();
    if (tid < BB*2){
      int b=tid>>1, k=tid&1;
      float s = f2b[k];
      #pragma unroll
      for (int q2=0;q2<16;q2++) s += h1s[b][q2]*f2W[k*16+q2];
      h2s[b][k] = sigmf(s);
    }
    __syncthreads();
    if (tid < BB*EE){
      int b=tid/EE, e=tid-b*EE;
      float xe = f3b[e] + f3W[e*2]*h2s[b][0] + f3W[e*2+1]*h2s[b][1];
      nv[((size_t)b*NN+n)*EE+e] =
        tanhf(emb[(((size_t)b*TT+(t+1))*NN+n)*EE+e]*xe);
    }
  } else {
    if (tid < BB*TT){
      int b = tid/TT, ot = tid - b*TT;
      const float* pw = predW + ((size_t)c*TT + ot)*HH;
      float pv = predB[c*TT+ot];
      #pragma unroll
      for (int q2=0;q2<HH;q2++) pv += hs[b][q2]*pw[q2];
      size_t oi = ((size_t)b*TT+ot)*NN + n;
      if (c == 0){
        out[oi] = pv;
        const float* sw = skipW + (size_t)ot*HH;
        float sk = skipB[ot];
        #pragma unroll
        for (int q2=0;q2<HH;q2++) sk += hs[b][q2]*sw[q2];
        cur[(((size_t)TT+ot)*BB + b)*NN + n] =
            cur[((size_t)ot*BB + b)*NN + n] - sk;
      } else {
        out[oi] += pv;
      }
    }
  }
}

extern "C" void kernel_launch(void* const* d_in, const int* in_sizes, int n_in,
                              void* d_out, int out_size, void* d_ws, size_t ws_size,
                              hipStream_t stream){
  const float* src  = (const float*)d_in[0];
  const float* ne   = (const float*)d_in[1];
  const float* te   = (const float*)d_in[2];
  const float* de   = (const float*)d_in[3];
  const float* wp_g = (const float*)d_in[4];
  const float* bp_g = (const float*)d_in[5];
  const float* f1W_g= (const float*)d_in[6];
  const float* f1b_g= (const float*)d_in[7];
  const float* f2W_g= (const float*)d_in[8];
  const float* f2b_g= (const float*)d_in[9];
  const float* f3W_g= (const float*)d_in[10];
  const float* f3b_g= (const float*)d_in[11];
  const float* wp_u = (const float*)d_in[12];
  const float* bp_u = (const float*)d_in[13];
  const float* f1W_u= (const float*)d_in[14];
  const float* f1b_u= (const float*)d_in[15];
  const float* f2W_u= (const float*)d_in[16];
  const float* f2b_u= (const float*)d_in[17];
  const float* f3W_u= (const float*)d_in[18];
  const float* f3b_u= (const float*)d_in[19];
  const float* predW= (const float*)d_in[20];
  const float* predB= (const float*)d_in[21];
  const float* skipW= (const float*)d_in[22];
  const float* skipB= (const float*)d_in[23];

  float* ws   = (float*)d_ws;
  float* emb  = ws;
  float* cur  = emb  + (size_t)BB*TT*NN*EE;
  float* wg   = cur  + (size_t)2*TT*BB*NN;
  float* bg   = wg   + (size_t)NN*2*NI4*OG*4;
  float* wu   = bg   + (size_t)NN*OG;
  float* bu   = wu   + (size_t)NN*2*NI4*OU*4;
  float* h    = bu   + (size_t)NN*OU;
  float* xsg  = h    + (size_t)BB*NN*HH;
  float* xsu  = xsg  + (size_t)BB*NN*XSP;
  float* nv   = xsu  + (size_t)BB*NN*XSP;
  float* dbuf = nv   + (size_t)BB*NN*EE;
  float* parts= dbuf + (size_t)BB*NN;
  float* rbuf = parts+ (size_t)JS*BB*NP*XSP;
  float* outp = (float*)d_out;

  k_emb<<<(BB*TT*NN+255)/256, 256, 0, stream>>>(src, ne, te, de, emb, cur);

  for (int c=0;c<2;c++){
    k_prep_w4m<<<dim3(2*NI4,4,2),256,0,stream>>>(ne,
        wp_g + (size_t)c*EE*2*DIN*OG, wp_u + (size_t)c*EE*2*DIN*OU, wg, wu);
    k_misc<<<1024,256,0,stream>>>(ne, bp_g + (size_t)c*EE*OG, bp_u + (size_t)c*EE*OU,
        bg, bu, h, cur + (size_t)c*TT*BB*NN,
        f1W_g + c*16*DIN, f1b_g + c*16, f2W_g + c*32, f2b_g + c*2,
        f3W_g + c*EE*2, f3b_g + c*EE, emb, xsg, nv);
    for (int t=0;t<TT;t++){
      k_xg2d<<<dim3(JS,BB),256,0,stream>>>(nv, xsg, parts, dbuf);
      k_tr_gate<<<NN,256,0,stream>>>(wg, bg, parts, dbuf, xsg,
          cur + ((size_t)c*TT+t)*BB*NN, h, emb, t,
          f1W_u + c*16*DIN, f1b_u + c*16, f2W_u + c*32, f2b_u + c*2,
          f3W_u + c*EE*2, f3b_u + c*EE, rbuf, xsu, nv);
      k_xg2d<<<dim3(JS,BB),256,0,stream>>>(nv, xsu, parts, dbuf);
      k_tr_upd<<<NN,256,0,stream>>>(wu, bu, parts, dbuf, xsu, rbuf, h,
          cur, c, t, emb,
          f1W_g + c*16*DIN, f1b_g + c*16, f2W_g + c*32, f2b_g + c*2,
          f3W_g + c*EE*2, f3b_g + c*EE,
          xsg, nv, predW, predB, skipW, skipB, outp);
    }
  }
}